// Round 4
// baseline (674.606 us; speedup 1.0000x reference)
//
#include <hip/hip_runtime.h>

#define KDIM 8192
#define NDIM 16384
#define BDIM 16
#define NBLK 8                        // KDIM/1024 scale blocks per row
#define TN 4                          // output rows per wave
#define WAVES 4
#define ROWS_PER_BLOCK (TN * WAVES)   // 16
#define CHUNK 256                     // k-elements per wave per chunk (64 lanes * 4)
#define NCHUNK (KDIM / CHUNK)         // 32

// Latency-bound fix vs round 3: TN 8->4 doubles wave count (16 waves/CU),
// manual 2-deep double-buffer keeps next chunk's W loads in flight during
// the FMA block. acc[16][4] = 64 VGPRs; cap at 128 via launch_bounds(256,4).
__global__ __launch_bounds__(256, 4) void int8lin_kernel(
    const float* __restrict__ x,
    const int* __restrict__ qw,
    const float* __restrict__ scales,
    const float* __restrict__ bias,
    float* __restrict__ out)
{
    const int lane = threadIdx.x & 63;
    const int wave = threadIdx.x >> 6;
    const int n0 = blockIdx.x * ROWS_PER_BLOCK + wave * TN;
    const int kbase = lane * 4;

    float acc[BDIM][TN];
#pragma unroll
    for (int i = 0; i < BDIM; ++i)
#pragma unroll
        for (int j = 0; j < TN; ++j) acc[i][j] = 0.f;

    const int* qrow[TN];
#pragma unroll
    for (int j = 0; j < TN; ++j) qrow[j] = qw + (size_t)(n0 + j) * KDIM + kbase;

#define LOADW(buf, c)                                                        \
    _Pragma("unroll")                                                        \
    for (int j = 0; j < TN; ++j)                                             \
        buf[j] = *reinterpret_cast<const int4*>(qrow[j] + (c) * CHUNK);

#define COMPUTE(buf, c)                                                      \
    do {                                                                     \
        float s_[TN], wf_[TN][4];                                            \
        _Pragma("unroll")                                                    \
        for (int j = 0; j < TN; ++j)                                         \
            s_[j] = scales[(size_t)(n0 + j) * NBLK + ((c) >> 2)];            \
        _Pragma("unroll")                                                    \
        for (int j = 0; j < TN; ++j) {                                       \
            wf_[j][0] = (float)buf[j].x * s_[j];                             \
            wf_[j][1] = (float)buf[j].y * s_[j];                             \
            wf_[j][2] = (float)buf[j].z * s_[j];                             \
            wf_[j][3] = (float)buf[j].w * s_[j];                             \
        }                                                                    \
        const int k0_ = (c) * CHUNK + kbase;                                 \
        _Pragma("unroll")                                                    \
        for (int i = 0; i < BDIM; ++i) {                                     \
            const float4 xv = *reinterpret_cast<const float4*>(              \
                x + (size_t)i * KDIM + k0_);                                 \
            _Pragma("unroll")                                                \
            for (int j = 0; j < TN; ++j) {                                   \
                acc[i][j] = fmaf(xv.x, wf_[j][0], acc[i][j]);                \
                acc[i][j] = fmaf(xv.y, wf_[j][1], acc[i][j]);                \
                acc[i][j] = fmaf(xv.z, wf_[j][2], acc[i][j]);                \
                acc[i][j] = fmaf(xv.w, wf_[j][3], acc[i][j]);                \
            }                                                                \
        }                                                                    \
    } while (0)

    int4 wA[TN], wB[TN];
    LOADW(wA, 0);

    for (int c = 0; c < NCHUNK; c += 2) {
        LOADW(wB, c + 1);
        COMPUTE(wA, c);
        const int cn = (c + 2 < NCHUNK) ? c + 2 : NCHUNK - 1;  // wrap, avoid OOB
        LOADW(wA, cn);
        COMPUTE(wB, c + 1);
    }

    // 64-lane butterfly reduction per accumulator.
#pragma unroll
    for (int i = 0; i < BDIM; ++i)
#pragma unroll
        for (int j = 0; j < TN; ++j) {
            float v = acc[i][j];
#pragma unroll
            for (int off = 32; off >= 1; off >>= 1) v += __shfl_xor(v, off, 64);
            acc[i][j] = v;
        }

    if (lane == 0) {
#pragma unroll
        for (int j = 0; j < TN; ++j) {
            const float b = bias[n0 + j];
#pragma unroll
            for (int i = 0; i < BDIM; ++i)
                out[(size_t)i * NDIM + (n0 + j)] = acc[i][j] + b;
        }
    }
}

extern "C" void kernel_launch(void* const* d_in, const int* in_sizes, int n_in,
                              void* d_out, int out_size, void* d_ws, size_t ws_size,
                              hipStream_t stream) {
    const float* x      = (const float*)d_in[0];
    const int*   qw     = (const int*)d_in[1];
    const float* scales = (const float*)d_in[2];
    const float* bias   = (const float*)d_in[3];
    float*       out    = (float*)d_out;

    dim3 grid(NDIM / ROWS_PER_BLOCK);   // 1024 blocks = 4 per CU
    dim3 block(256);                     // 4 waves
    int8lin_kernel<<<grid, block, 0, stream>>>(x, qw, scales, bias, out);
}

// Round 5
// 350.472 us; speedup vs baseline: 1.9248x; 1.9248x over previous
//
#include <hip/hip_runtime.h>

#define KDIM 8192
#define NDIM 16384
#define BDIM 16
#define NBLK 8                        // KDIM/1024 scale blocks per row
#define TN 8                          // output rows per wave
#define WAVES 4
#define ROWS_PER_BLOCK (TN * WAVES)   // 32
#define KC 256                        // k-elements per chunk (64 lanes * 4)
#define NCHUNK (KDIM / KC)            // 32

// Direct global->LDS 16B async copy: LDS dest = wave-uniform base + lane*16,
// global src = per-lane address (m97 pattern, linear LDS layout).
__device__ __forceinline__ void gload_lds16(const int* g, int* l) {
    __builtin_amdgcn_global_load_lds(
        (const __attribute__((address_space(1))) unsigned int*)(uintptr_t)g,
        (__attribute__((address_space(3))) unsigned int*)(uintptr_t)l,
        16, 0, 0);
}

// out[16,16384] f32 = x[16,8192] f32 . dequant(qw int32(int8), per-1024-block
// f32 scales)^T + bias. Wave owns 8 N-rows; W staged via global_load_lds
// (depth in LDS, not VGPRs); wave-local vmcnt(0) sync, no block barrier.
__global__ __launch_bounds__(256, 2) void int8lin_kernel(
    const float* __restrict__ x,
    const int* __restrict__ qw,
    const float* __restrict__ scales,
    const float* __restrict__ bias,
    float* __restrict__ out)
{
    __shared__ int lds_w[ROWS_PER_BLOCK][KC];   // 32 KB

    const int lane = threadIdx.x & 63;
    const int wave = threadIdx.x >> 6;
    const int n0 = blockIdx.x * ROWS_PER_BLOCK + wave * TN;

    float acc[BDIM][TN];
#pragma unroll
    for (int i = 0; i < BDIM; ++i)
#pragma unroll
        for (int j = 0; j < TN; ++j) acc[i][j] = 0.f;

    const int kbase = lane * 4;                 // lane's 4 ints per chunk
    int* lrow0 = &lds_w[wave * TN][0];          // wave-uniform LDS base

#pragma unroll 1
    for (int c = 0; c < NCHUNK; ++c) {
        // Fence: previous chunk's compute fully issued before LDS is rewritten
        // (single buffer; issued ds_reads complete ~120cy, HBM writeback ~900cy).
        __builtin_amdgcn_sched_barrier(0);

        // Stage this chunk's 8 W rows (1 KB each) into LDS.
#pragma unroll
        for (int r = 0; r < TN; ++r)
            gload_lds16(qw + (size_t)(n0 + r) * KDIM + c * KC + kbase,
                        lrow0 + r * KC);

        asm volatile("s_waitcnt vmcnt(0)" ::: "memory");
        __builtin_amdgcn_sched_barrier(0);

        // Dequantize lane's 4 ints of each of the 8 rows.
        float s[TN], wf[TN][4];
#pragma unroll
        for (int j = 0; j < TN; ++j)
            s[j] = scales[(size_t)(n0 + j) * NBLK + (c >> 2)];
#pragma unroll
        for (int j = 0; j < TN; ++j) {
            const int4 w = *reinterpret_cast<const int4*>(&lds_w[wave * TN + j][kbase]);
            wf[j][0] = (float)w.x * s[j];
            wf[j][1] = (float)w.y * s[j];
            wf[j][2] = (float)w.z * s[j];
            wf[j][3] = (float)w.w * s[j];
        }

        const int k0 = c * KC + kbase;
#pragma unroll
        for (int i = 0; i < BDIM; ++i) {
            const float4 xv = *reinterpret_cast<const float4*>(x + (size_t)i * KDIM + k0);
#pragma unroll
            for (int j = 0; j < TN; ++j) {
                acc[i][j] = fmaf(xv.x, wf[j][0], acc[i][j]);
                acc[i][j] = fmaf(xv.y, wf[j][1], acc[i][j]);
                acc[i][j] = fmaf(xv.z, wf[j][2], acc[i][j]);
                acc[i][j] = fmaf(xv.w, wf[j][3], acc[i][j]);
            }
        }
    }

    // 64-lane butterfly reduction per accumulator.
#pragma unroll
    for (int i = 0; i < BDIM; ++i)
#pragma unroll
        for (int j = 0; j < TN; ++j) {
            float v = acc[i][j];
#pragma unroll
            for (int off = 32; off >= 1; off >>= 1) v += __shfl_xor(v, off, 64);
            acc[i][j] = v;
        }

    if (lane == 0) {
#pragma unroll
        for (int j = 0; j < TN; ++j) {
            const float b = bias[n0 + j];
#pragma unroll
            for (int i = 0; i < BDIM; ++i)
                out[(size_t)i * NDIM + (n0 + j)] = acc[i][j] + b;
        }
    }
}

extern "C" void kernel_launch(void* const* d_in, const int* in_sizes, int n_in,
                              void* d_out, int out_size, void* d_ws, size_t ws_size,
                              hipStream_t stream) {
    const float* x      = (const float*)d_in[0];
    const int*   qw     = (const int*)d_in[1];
    const float* scales = (const float*)d_in[2];
    const float* bias   = (const float*)d_in[3];
    float*       out    = (float*)d_out;

    dim3 grid(NDIM / ROWS_PER_BLOCK);   // 512 blocks = 2 per CU
    dim3 block(256);                     // 4 waves
    int8lin_kernel<<<grid, block, 0, stream>>>(x, qw, scales, bias, out);
}

// Round 6
// 216.311 us; speedup vs baseline: 3.1187x; 1.6202x over previous
//
#include <hip/hip_runtime.h>

#define KDIM 8192
#define NDIM 16384
#define BDIM 16
#define NBLK 8                      // KDIM/1024 scale blocks per row

// Lane-per-row streaming dequant-GEMM partial kernel.
// grid = (NDIM/256, ksplit), block = 256 (4 waves, 64 rows each).
// Lane owns row n = blockIdx.x*256 + threadIdx.x; accumulates 16 batch dots
// over its K-slice into acc[16]; writes partials (or final, if direct).
__global__ __launch_bounds__(256, 4) void int8lin_partial(
    const float* __restrict__ x,
    const int* __restrict__ qw,
    const float* __restrict__ scales,
    const float* __restrict__ bias,
    float* __restrict__ part,        // [ksplit][16][NDIM], or out if direct
    int kslice, int direct)
{
    const int n = blockIdx.x * 256 + threadIdx.x;
    const int s = blockIdx.y;
    const int k0 = s * kslice;
    const int kend = k0 + kslice;

    float acc[BDIM];
#pragma unroll
    for (int i = 0; i < BDIM; ++i) acc[i] = 0.f;

    const int* wp = qw + (size_t)n * KDIM;   // this lane's weight row

    for (int kb = k0; kb < kend; kb += 1024) {          // scale-block granularity
        const float sc = scales[n * NBLK + (kb >> 10)];
        const int klim = (kend - kb < 1024) ? (kend - kb) : 1024;
#pragma unroll 2
        for (int kk = 0; kk < klim; kk += 4) {
            const int k = kb + kk;
            const int4 w = *reinterpret_cast<const int4*>(wp + k);
            const float w0 = (float)w.x * sc;
            const float w1 = (float)w.y * sc;
            const float w2 = (float)w.z * sc;
            const float w3 = (float)w.w * sc;
            // x is wave-uniform: all lanes read the same 16B (broadcast).
#pragma unroll
            for (int i = 0; i < BDIM; ++i) {
                const float4 xv = *reinterpret_cast<const float4*>(x + (size_t)i * KDIM + k);
                acc[i] = fmaf(xv.x, w0, acc[i]);
                acc[i] = fmaf(xv.y, w1, acc[i]);
                acc[i] = fmaf(xv.z, w2, acc[i]);
                acc[i] = fmaf(xv.w, w3, acc[i]);
            }
        }
    }

    if (direct) {
        const float b = bias[n];
#pragma unroll
        for (int i = 0; i < BDIM; ++i)
            part[(size_t)i * NDIM + n] = acc[i] + b;
    } else {
#pragma unroll
        for (int i = 0; i < BDIM; ++i)
            part[((size_t)(s * BDIM + i) << 14) + n] = acc[i];
    }
}

// out[i][n] = sum_s part[s][i][n] + bias[n]; one thread per output element.
__global__ __launch_bounds__(256) void int8lin_reduce(
    const float* __restrict__ part,
    const float* __restrict__ bias,
    float* __restrict__ out, int ksplit)
{
    const int idx = blockIdx.x * 256 + threadIdx.x;   // i*NDIM + n
    const int n = idx & (NDIM - 1);
    const int i = idx >> 14;
    float v = bias[n];
    for (int s = 0; s < ksplit; ++s)
        v += part[((size_t)(s * BDIM + i) << 14) + n];
    out[idx] = v;
}

extern "C" void kernel_launch(void* const* d_in, const int* in_sizes, int n_in,
                              void* d_out, int out_size, void* d_ws, size_t ws_size,
                              hipStream_t stream) {
    const float* x      = (const float*)d_in[0];
    const int*   qw     = (const int*)d_in[1];
    const float* scales = (const float*)d_in[2];
    const float* bias   = (const float*)d_in[3];
    float*       out    = (float*)d_out;

    const size_t per_split = (size_t)BDIM * NDIM * sizeof(float);   // 1 MB

    int ksplit = 1;
    while (ksplit < 16 && (size_t)(ksplit * 2) * per_split <= ws_size) ksplit *= 2;

    if (ws_size >= per_split) {
        float* part = (float*)d_ws;
        dim3 grid(NDIM / 256, ksplit);
        int8lin_partial<<<grid, 256, 0, stream>>>(x, qw, scales, bias, part,
                                                  KDIM / ksplit, 0);
        int8lin_reduce<<<(BDIM * NDIM) / 256, 256, 0, stream>>>(part, bias, out, ksplit);
    } else {
        // Fallback: no workspace — single split writes out directly (slow but correct).
        dim3 grid(NDIM / 256, 1);
        int8lin_partial<<<grid, 256, 0, stream>>>(x, qw, scales, bias, out, KDIM, 1);
    }
}

// Round 7
// 140.083 us; speedup vs baseline: 4.8158x; 1.5442x over previous
//
#include <hip/hip_runtime.h>

#define KDIM 8192
#define NDIM 16384
#define BDIM 16
#define NBLK 8                        // KDIM/1024 scale blocks per row
#define TN 4                          // output rows per wave
#define WAVES 4
#define ROWS_PER_BLOCK (WAVES * TN)   // 16
#define KC 256                        // k-elements per chunk
#define NCHUNK (KDIM / KC)            // 32

// global->LDS direct copy, 16B/lane: LDS dest wave-uniform, global src per-lane.
__device__ __forceinline__ void gload_lds16(const float* g, float* l) {
    __builtin_amdgcn_global_load_lds(
        (const __attribute__((address_space(1))) unsigned int*)(uintptr_t)g,
        (__attribute__((address_space(3))) unsigned int*)(uintptr_t)l,
        16, 0, 0);
}

// Block owns 16 N-rows over full K. x chunk (16x256 f32) double-buffered in LDS
// (shared by 4 waves); W coalesced int4 loads, register double-buffered one
// compute-phase ahead. acc[16][4]=64 VGPRs -> compiler has pipelining headroom.
__global__ __launch_bounds__(256) void int8lin_kernel(
    const float* __restrict__ x,
    const int* __restrict__ qw,
    const float* __restrict__ scales,
    const float* __restrict__ bias,
    float* __restrict__ out)
{
    __shared__ float xbuf[2][BDIM][KC];   // 2 x 16 KB

    const int lane = threadIdx.x & 63;
    const int wave = threadIdx.x >> 6;
    const int n0 = blockIdx.x * ROWS_PER_BLOCK + wave * TN;
    const int kbase = lane * 4;

    float acc[BDIM][TN];
#pragma unroll
    for (int i = 0; i < BDIM; ++i)
#pragma unroll
        for (int j = 0; j < TN; ++j) acc[i][j] = 0.f;

    // Stage x chunk c into xbuf[pb]: wave w stages batch rows 4w..4w+3.
    auto STAGE = [&](int c, int pb) {
#pragma unroll
        for (int q = 0; q < 4; ++q) {
            const int i = wave * 4 + q;
            gload_lds16(x + (size_t)i * KDIM + c * KC + kbase, &xbuf[pb][i][0]);
        }
    };

    auto LOADW = [&](int4* w, int c) {
#pragma unroll
        for (int j = 0; j < TN; ++j)
            w[j] = *reinterpret_cast<const int4*>(qw + (size_t)(n0 + j) * KDIM + c * KC + kbase);
    };

    auto COMPUTE = [&](const int4* w, int c, int pb) {
        float s[TN], wf[TN][4];
#pragma unroll
        for (int j = 0; j < TN; ++j)
            s[j] = scales[(size_t)(n0 + j) * NBLK + (c >> 2)];
#pragma unroll
        for (int j = 0; j < TN; ++j) {
            wf[j][0] = (float)w[j].x * s[j];
            wf[j][1] = (float)w[j].y * s[j];
            wf[j][2] = (float)w[j].z * s[j];
            wf[j][3] = (float)w[j].w * s[j];
        }
#pragma unroll
        for (int i = 0; i < BDIM; ++i) {
            const float4 xv = *reinterpret_cast<const float4*>(&xbuf[pb][i][kbase]);
#pragma unroll
            for (int j = 0; j < TN; ++j) {
                acc[i][j] = fmaf(xv.x, wf[j][0], acc[i][j]);
                acc[i][j] = fmaf(xv.y, wf[j][1], acc[i][j]);
                acc[i][j] = fmaf(xv.z, wf[j][2], acc[i][j]);
                acc[i][j] = fmaf(xv.w, wf[j][3], acc[i][j]);
            }
        }
    };

    int4 wA[TN], wB[TN];
    STAGE(0, 0);
    LOADW(wA, 0);

#pragma unroll 1
    for (int c = 0; c < NCHUNK; c += 2) {
        __syncthreads();                 // xbuf[0] (chunk c) ready; wA drained
        STAGE(c + 1, 1);                 // async: x[c+1] in flight under compute
        LOADW(wB, c + 1);
        COMPUTE(wA, c, 0);

        __syncthreads();                 // xbuf[1] (chunk c+1) ready; wB drained
        if (c + 2 < NCHUNK) {
            STAGE(c + 2, 0);
            LOADW(wA, c + 2);
        }
        COMPUTE(wB, c + 1, 1);
    }

    // 64-lane butterfly reduction; then lane 0 stores its wave's 16x4 tile.
#pragma unroll
    for (int i = 0; i < BDIM; ++i)
#pragma unroll
        for (int j = 0; j < TN; ++j) {
            float v = acc[i][j];
#pragma unroll
            for (int off = 32; off >= 1; off >>= 1) v += __shfl_xor(v, off, 64);
            acc[i][j] = v;
        }

    if (lane == 0) {
#pragma unroll
        for (int j = 0; j < TN; ++j) {
            const float b = bias[n0 + j];
#pragma unroll
            for (int i = 0; i < BDIM; ++i)
                out[(size_t)i * NDIM + (n0 + j)] = acc[i][j] + b;
        }
    }
}

extern "C" void kernel_launch(void* const* d_in, const int* in_sizes, int n_in,
                              void* d_out, int out_size, void* d_ws, size_t ws_size,
                              hipStream_t stream) {
    const float* x      = (const float*)d_in[0];
    const int*   qw     = (const int*)d_in[1];
    const float* scales = (const float*)d_in[2];
    const float* bias   = (const float*)d_in[3];
    float*       out    = (float*)d_out;

    dim3 grid(NDIM / ROWS_PER_BLOCK);   // 1024 blocks = 4 per CU
    dim3 block(256);                     // 4 waves
    int8lin_kernel<<<grid, block, 0, stream>>>(x, qw, scales, bias, out);
}